// Round 2
// baseline (187.466 us; speedup 1.0000x reference)
//
#include <hip/hip_runtime.h>

// Problem constants (fixed by reference: B=64, T=1024, D=256)
constexpr int Bn = 64;
constexpr int Tn = 1024;
constexpr int Dn = 256;

constexpr int TPB   = 256;        // 4 waves
constexpr int RG    = 16;         // rows staged per group
constexpr int NG    = Bn / RG;    // 4 groups per t
constexpr int PITCH = Dn + 4;     // 260 floats (pad keeps write phases uniform)

__device__ __forceinline__ float dot4(const float4& a, const float4& b) {
    return a.x * b.x + a.y * b.y + a.z * b.z + a.w * b.w;
}

// Factorized cross term:
//   Sigma_{i!=j,t,d} vn_i an_j = Sigma_{t,d} (Sigma_i vn_i)(Sigma_j an_j) - Sigma_{i,t} cos_it
// so no 64x64 GEMM: just per-(t,d) column sums of norm-scaled rows.
__global__ __launch_bounds__(TPB, 4)   // 4 waves/EU -> 4 blocks/CU (16 waves/CU)
void cmfm_main(const float* __restrict__ fv, const float* __restrict__ fa,
               const int* __restrict__ labels, float* __restrict__ acc) {
    __shared__ __align__(16) float Vs[RG][PITCH];
    __shared__ __align__(16) float As[RG][PITCH];
    __shared__ float rvl[RG];
    __shared__ float ral[RG];
    __shared__ float wred[4][TPB / 64];

    const int tid = threadIdx.x;
    const int r16 = tid >> 4;     // row-within-group 0..15
    const int dp  = tid & 15;     // d-part 0..15 (each owns 4 float4s of the row)
    const int t   = blockIdx.x;   // one timestep per block

    const float4* __restrict__ fv4 = reinterpret_cast<const float4*>(fv);
    const float4* __restrict__ fa4 = reinterpret_cast<const float4*>(fa);

    float pos_acc = 0.f, neg_acc = 0.f, diag_acc = 0.f;
    float svd = 0.f, sad = 0.f;   // column sums for d == tid

    for (int g = 0; g < NG; ++g) {
        const int row = g * RG + r16;
        const size_t base = ((size_t)row * Tn + t) * (Dn / 4);

        // ---- load 16 rows (full D) to registers; accumulate norm partials ----
        float4 v4[4], a4[4];
        #pragma unroll
        for (int k = 0; k < 4; ++k) {
            v4[k] = fv4[base + dp + 16 * k];
            a4[k] = fa4[base + dp + 16 * k];
        }
        float sqv = 0.f, sqa = 0.f, dva = 0.f;
        #pragma unroll
        for (int k = 0; k < 4; ++k) {
            sqv += dot4(v4[k], v4[k]);
            sqa += dot4(a4[k], a4[k]);
            dva += dot4(v4[k], a4[k]);
            const int d = (dp + 16 * k) * 4;
            *reinterpret_cast<float4*>(&Vs[r16][d]) = v4[k];
            *reinterpret_cast<float4*>(&As[r16][d]) = a4[k];
        }
        // ---- per-row reduction across the 16 d-part lanes (stays in-wave) ----
        #pragma unroll
        for (int off = 1; off < 16; off <<= 1) {
            sqv += __shfl_xor(sqv, off);
            sqa += __shfl_xor(sqa, off);
            dva += __shfl_xor(dva, off);
        }
        if (dp == 0) {
            const float rv = 1.f / fmaxf(sqrtf(sqv), 1e-8f);
            const float ra = 1.f / fmaxf(sqrtf(sqa), 1e-8f);
            rvl[r16] = rv;
            ral[r16] = ra;
            const float cosd = dva * rv * ra;
            diag_acc += cosd;                            // Sigma_i cos (cross diagonal)
            if (labels[row] == 0) pos_acc += 1.f - cosd; // ALPHA term: d_bt
            else                  neg_acc += cosd;       // BETA term: 1 - d_bt
        }
        __syncthreads();

        // ---- column sums: thread owns d = tid; contiguous LDS reads (2-way, free) ----
        #pragma unroll
        for (int i = 0; i < RG; ++i) {
            svd = fmaf(rvl[i], Vs[i][tid], svd);
            sad = fmaf(ral[i], As[i][tid], sad);
        }
        __syncthreads();   // before next group overwrites Vs/As/rvl/ral
    }

    // ---- this t's factorized dot + block reduction ----
    float dotp = svd * sad;
    #pragma unroll
    for (int off = 1; off < 64; off <<= 1) {
        pos_acc  += __shfl_xor(pos_acc, off);
        neg_acc  += __shfl_xor(neg_acc, off);
        diag_acc += __shfl_xor(diag_acc, off);
        dotp     += __shfl_xor(dotp, off);
    }
    const int wave = tid >> 6;
    const int lane = tid & 63;
    if (lane == 0) {
        wred[0][wave] = pos_acc;
        wred[1][wave] = neg_acc;
        wred[2][wave] = dotp;
        wred[3][wave] = diag_acc;
    }
    __syncthreads();
    if (tid == 0) {
        float p = 0.f, n = 0.f, o = 0.f, dg = 0.f;
        #pragma unroll
        for (int w = 0; w < TPB / 64; ++w) {
            p += wred[0][w]; n += wred[1][w]; o += wred[2][w]; dg += wred[3][w];
        }
        atomicAdd(&acc[0], p);
        atomicAdd(&acc[1], n);
        atomicAdd(&acc[2], o);
        atomicAdd(&acc[3], dg);
    }
}

__global__ void cmfm_final(const int* __restrict__ labels, const float* __restrict__ acc,
                           float* __restrict__ out) {
    if (threadIdx.x == 0) {
        int npos = 0;
        for (int i = 0; i < Bn; ++i) npos += (labels[i] == 0);
        const float pos_sum  = acc[0];
        const float neg_sum  = acc[1];
        const float dot_sum  = acc[2];   // Sigma_t Sigma_d (Sigma_i vn)(Sigma_j an)
        const float diag_sum = acc[3];   // Sigma_{i,t} cos_it
        const float cross_sum = dot_sum - diag_sum;   // Sigma_{i!=j} Sigma_t vn_i.an_j

        const float cnt_pos = (float)npos * (float)Tn;
        const float cnt_neg = (float)(Bn - npos) * (float)Tn + (float)Bn * (float)(Bn - 1);

        float loss = 0.f;
        if (npos > 0) loss += 2.0f * pos_sum / cnt_pos;                       // ALPHA
        loss += (2.0f * neg_sum + 1.0f * cross_sum / (float)Tn) / cnt_neg;    // BETA, GAMMA
        out[0] = loss;
    }
}

extern "C" void kernel_launch(void* const* d_in, const int* in_sizes, int n_in,
                              void* d_out, int out_size, void* d_ws, size_t ws_size,
                              hipStream_t stream) {
    const float* fv     = (const float*)d_in[0];
    const float* fa     = (const float*)d_in[1];
    const int*   labels = (const int*)d_in[2];
    float* acc = (float*)d_ws;   // [0]=pos [1]=neg [2]=dot [3]=diag
    float* out = (float*)d_out;

    hipMemsetAsync(acc, 0, 4 * sizeof(float), stream);
    cmfm_main<<<Tn, TPB, 0, stream>>>(fv, fa, labels, acc);
    cmfm_final<<<1, 64, 0, stream>>>(labels, acc, out);
}